// Round 9
// baseline (1331.507 us; speedup 1.0000x reference)
//
#include <hip/hip_runtime.h>
#include <hip/hip_bf16.h>
#include <cstdio>

#define TB  8192
#define N_  24
#define D_  256
#define H_  8
#define F_  32
#define ND  6144      // N_*D_
#define HNF 6144      // H_*N_*F_

typedef unsigned short u16;
typedef __attribute__((ext_vector_type(8))) _Float16 f16x8;
typedef __attribute__((ext_vector_type(8))) short bf16x8;
typedef __attribute__((ext_vector_type(4))) float f32x4;

__device__ __forceinline__ u16 f2b(float f) {
    unsigned int u = __float_as_uint(f);
    return (u16)((u + 0x7FFFu + ((u >> 16) & 1u)) >> 16);
}
__device__ __forceinline__ float b2f(u16 s) {
    return __uint_as_float(((unsigned int)s) << 16);
}
__device__ __forceinline__ u16 f2h(float f) {
    _Float16 h = (_Float16)f;
    u16 u; __builtin_memcpy(&u, &h, 2); return u;
}

__device__ __forceinline__ void gl_lds16(const void* g, void* l) {
    __builtin_amdgcn_global_load_lds(
        (const __attribute__((address_space(1))) unsigned int*)g,
        (__attribute__((address_space(3))) unsigned int*)l, 16, 0, 0);
}

// ---------- prep: weights -> fp16, layout [n][kt][g(48)][fq(4)][fr(16)][8] ----------
__global__ __launch_bounds__(256) void prep_weights(
    const float* __restrict__ Wk, const float* __restrict__ Wv,
    const float* __restrict__ Wq, u16* __restrict__ Bp)
{
    const int idx = blockIdx.x * 256 + threadIdx.x;   // 0 .. 589823
    if (idx >= 24 * 8 * 48 * 64) return;
    const int fr = idx & 15;
    const int fq = (idx >> 4) & 3;
    const int g  = (idx >> 6) % 48;
    const int kt = (idx / (64 * 48)) % 8;
    const int n  = idx / (64 * 48 * 8);
    const int col = g * 16 + fr;
    const int d0  = kt * 32 + fq * 8;
    const int c   = col & 255;
    const float* src;
    if (col < 256)      src = Wk + (size_t)c * 256 + d0;
    else if (col < 512) src = Wv + (size_t)c * 256 + d0;
    else {
        const int h = c >> 5, f = c & 31;
        src = Wq + ((size_t)(h * 24 + n) * 32 + f) * 256 + d0;
    }
    __align__(16) u16 out[8];
    #pragma unroll
    for (int j = 0; j < 8; ++j) out[j] = f2h(src[j]);
    *reinterpret_cast<uint4*>(Bp + (size_t)idx * 8) =
        *reinterpret_cast<const uint4*>(out);
}

__global__ __launch_bounds__(256) void prep_bias(
    const float* __restrict__ bk, const float* __restrict__ bv,
    const float* __restrict__ bq, float* __restrict__ biasp)
{
    const int idx = blockIdx.x * 256 + threadIdx.x;
    if (idx >= 24 * 768) return;
    const int col = idx % 768, n = idx / 768;
    const int c = col & 255;
    float v;
    if (col < 256)      v = bk[c];
    else if (col < 512) v = bv[c];
    else { const int h = c >> 5, f = c & 31; v = bq[(h * 24 + n) * 32 + f]; }
    biasp[n * 768 + col] = v;
}

// ---------- proj v9: v7 pipeline + 48KB LDS (3 blocks/CU) + XCD-clustered
// groups + n-major contiguous output layout ----------
__global__ __launch_bounds__(512, 6) void proj_mfma(
    const float* __restrict__ x,
    const u16* __restrict__ Bp,
    const float* __restrict__ biasp,
    u16* __restrict__ kb, u16* __restrict__ vb, u16* __restrict__ qb)
{
    // b = xcd + 8*(gi + 9*mblk); grp = xcd*9 + gi. Each XCD owns 9 groups
    // (= exactly 3 joints n) -> B slice 1.15MB L2-resident, x tiles shared.
    const int b    = blockIdx.x;                 // 0..4607
    const int xcd  = b & 7;
    const int t    = b >> 3;                     // 0..575
    const int gi   = t % 9;
    const int mblk = t / 9;                      // 0..63
    const int grp  = xcd * 9 + gi;               // 0..71
    const int n    = grp / 3;
    const int ct   = grp % 3;                    // 0=K,1=V,2=Q
    const int tb0  = mblk * 128;
    const int tid  = threadIdx.x;
    const int w    = tid >> 6;                   // 0..7
    const int lane = tid & 63;
    const int wm   = w >> 2;                     // row half
    const int wn   = w & 3;                      // col quarter
    const int fr   = lane & 15, fq = lane >> 4;

    // LDS 48KB: A dbuf 2x8KB [0,16K) | B dbuf 2x16KB [16K,48K).
    // Epilogue reuses [0,32K) for 64-row passes.
    __shared__ __align__(16) char smem[49152];
    char* const Ab = smem;
    char* const Bb = smem + 16384;

    // A staging: thread -> (row 0..127, chunk 0..3 of 8 fp16)
    const int arow = tid >> 2;
    const int ac   = tid & 3;
    const float* xsrc = x + (size_t)(tb0 + arow) * ND + n * 256 + ac * 8;
    const int awbyte = arow * 64 + ((ac ^ ((arow >> 1) & 3)) << 4);

    const size_t bbase = (size_t)(n * 8 * 48 + ct * 16 + w * 2) * 1024 + lane * 16;

    f32x4 acc[4][4];
    #pragma unroll
    for (int m = 0; m < 4; ++m)
        #pragma unroll
        for (int j = 0; j < 4; ++j) acc[m][j] = (f32x4){0.f, 0.f, 0.f, 0.f};

    float4 axr[2][2];  // static-indexed under full unroll

    // ---- prologue: A(0), B(0); write A(0); issue A(1) ----
    axr[0][0] = *reinterpret_cast<const float4*>(xsrc);
    axr[0][1] = *reinterpret_cast<const float4*>(xsrc + 4);
    gl_lds16((const char*)Bp + bbase,        Bb + (w * 2) * 1024);
    gl_lds16((const char*)Bp + bbase + 1024, Bb + (w * 2 + 1) * 1024);
    asm volatile("s_waitcnt vmcnt(2)" ::: "memory");   // A(0) regs ready
    {
        ushort4 hv, hv2;
        hv.x  = f2h(axr[0][0].x); hv.y  = f2h(axr[0][0].y);
        hv.z  = f2h(axr[0][0].z); hv.w  = f2h(axr[0][0].w);
        hv2.x = f2h(axr[0][1].x); hv2.y = f2h(axr[0][1].y);
        hv2.z = f2h(axr[0][1].z); hv2.w = f2h(axr[0][1].w);
        *reinterpret_cast<ushort4*>(Ab + awbyte)     = hv;
        *reinterpret_cast<ushort4*>(Ab + awbyte + 8) = hv2;
    }
    axr[1][0] = *reinterpret_cast<const float4*>(xsrc + 32);
    axr[1][1] = *reinterpret_cast<const float4*>(xsrc + 36);
    asm volatile("s_waitcnt lgkmcnt(0)" ::: "memory");
    asm volatile("s_waitcnt vmcnt(2)" ::: "memory");   // B(0) landed
    __builtin_amdgcn_s_barrier();
    asm volatile("" ::: "memory");

    #pragma unroll
    for (int kt = 0; kt < 8; ++kt) {
        const int c = kt & 1, o = c ^ 1;

        // issue B(kt+1) -> other buf (stays in flight across compute)
        if (kt < 7) {
            const size_t bs = bbase + (size_t)(kt + 1) * 48 * 1024;
            gl_lds16((const char*)Bp + bs,        Bb + o * 16384 + (w * 2) * 1024);
            gl_lds16((const char*)Bp + bs + 1024, Bb + o * 16384 + (w * 2 + 1) * 1024);
        }

        // ---- compute(kt): 8 ds_read_b128 + 16 MFMA ----
        f16x8 bfr[4], afr[4];
        #pragma unroll
        for (int j = 0; j < 4; ++j)
            bfr[j] = *reinterpret_cast<const f16x8*>(
                Bb + c * 16384 + (wn * 4 + j) * 1024 + lane * 16);
        #pragma unroll
        for (int m = 0; m < 4; ++m) {
            const int row = wm * 64 + m * 16 + fr;
            afr[m] = *reinterpret_cast<const f16x8*>(
                Ab + c * 8192 + row * 64 + ((fq ^ ((fr >> 1) & 3)) << 4));
        }
        __builtin_amdgcn_s_setprio(1);
        #pragma unroll
        for (int j = 0; j < 4; ++j)
            #pragma unroll
            for (int m = 0; m < 4; ++m)
                acc[m][j] = __builtin_amdgcn_mfma_f32_16x16x32_f16(
                    afr[m], bfr[j], acc[m][j], 0, 0, 0);
        __builtin_amdgcn_s_setprio(0);

        if (kt < 7) {
            // A(kt+1) regs ready (oldest 2 of [A(kt+1), B(kt+1)])
            asm volatile("s_waitcnt vmcnt(2)" ::: "memory");
            __builtin_amdgcn_sched_barrier(0);
            {
                const float4 lo = axr[(kt + 1) & 1][0];
                const float4 hi = axr[(kt + 1) & 1][1];
                ushort4 hv, hv2;
                hv.x  = f2h(lo.x); hv.y  = f2h(lo.y); hv.z  = f2h(lo.z); hv.w  = f2h(lo.w);
                hv2.x = f2h(hi.x); hv2.y = f2h(hi.y); hv2.z = f2h(hi.z); hv2.w = f2h(hi.w);
                *reinterpret_cast<ushort4*>(Ab + o * 8192 + awbyte)     = hv;
                *reinterpret_cast<ushort4*>(Ab + o * 8192 + awbyte + 8) = hv2;
            }
            if (kt < 6) {
                axr[kt & 1][0] = *reinterpret_cast<const float4*>(xsrc + (kt + 2) * 32);
                axr[kt & 1][1] = *reinterpret_cast<const float4*>(xsrc + (kt + 2) * 32 + 4);
            }
            asm volatile("s_waitcnt lgkmcnt(0)" ::: "memory");
            if (kt < 6) {
                asm volatile("s_waitcnt vmcnt(2)" ::: "memory");   // B(kt+1) landed
            } else {
                asm volatile("s_waitcnt vmcnt(0)" ::: "memory");   // tail: drain B(7)
            }
            __builtin_amdgcn_s_barrier();
            asm volatile("" ::: "memory");
        }
    }
    __syncthreads();

    // ---- epilogue: two 64-row passes through 32KB swizzled LDS,
    // n-major output: dst[tb*6144 + n*256 + c] -> 512B contiguous per row ----
    u16* dst = (ct == 0) ? kb : (ct == 1) ? vb : qb;
    #pragma unroll
    for (int p = 0; p < 2; ++p) {
        if (wm == p) {
            #pragma unroll
            for (int j = 0; j < 4; ++j) {
                const int colL = wn * 64 + j * 16 + fr;
                const float bs = biasp[n * 768 + ct * 256 + colL];
                #pragma unroll
                for (int m = 0; m < 4; ++m)
                    #pragma unroll
                    for (int r = 0; r < 4; ++r) {
                        const int rowL = m * 16 + fq * 4 + r;   // 0..63
                        const int byte = (rowL * 512 + colL * 2) ^ ((rowL & 7) << 4);
                        *reinterpret_cast<u16*>(smem + byte) = f2b(acc[m][j][r] + bs);
                    }
            }
        }
        __syncthreads();
        #pragma unroll
        for (int it = 0; it < 4; ++it) {
            const int id  = it * 512 + tid;      // 0..2047 16B chunks
            const int row = id >> 5;             // 0..63
            const int cch = id & 31;
            const uint4 v = *reinterpret_cast<const uint4*>(
                smem + ((row * 512 + cch * 16) ^ ((row & 7) << 4)));
            *reinterpret_cast<uint4*>(
                &dst[(size_t)(tb0 + p * 64 + row) * HNF + n * 256 + cch * 8]) = v;
        }
        __syncthreads();
    }
}

// ---------------- attention: MFMA, one wave per tb, barrier-free ----------------
// q/k/v layout per tb: [n(24)][h(8)][f(32)] (n-major, c = h*32+f contiguous).
__device__ __forceinline__ int swz(int row, int chunk) {
    return row * 32 + (((chunk ^ ((row >> 1) ^ (row >> 3))) & 3) << 3);
}

__global__ __launch_bounds__(256) void attn_mfma(
    const u16* __restrict__ kb,
    const u16* __restrict__ vb,
    const u16* __restrict__ qb,
    float* __restrict__ out)
{
    const int tid  = threadIdx.x;
    const int wid  = tid >> 6;
    const int lane = tid & 63;
    const int fr   = lane & 15;
    const int fq   = lane >> 4;
    const size_t tb = (size_t)blockIdx.x * 4 + wid;

    __shared__ __align__(16) u16 lds[4][2048];
    u16* Pw = lds[wid];
    u16* Vt = lds[wid] + 1024;

    #pragma unroll
    for (int i = 0; i < 4; ++i)
        reinterpret_cast<uint4*>(lds[wid])[lane + i * 64] = (uint4){0, 0, 0, 0};

    const u16* qt = qb + tb * HNF;
    const u16* kt = kb + tb * HNF;
    const u16* vt = vb + tb * HNF;
    float* outp = out + tb * ND;

    const float scale = 0.17677669529663687f;
    const bool colok = fr < 8;

    for (int h = 0; h < H_; ++h) {
        const u16* qh = qt + h * 32;     // + n*256 + f
        const u16* kh = kt + h * 32;
        const u16* vh = vt + h * 32;

        bf16x8 qa[2], ka[2];
        #pragma unroll
        for (int t = 0; t < 2; ++t) {
            int rq = t * 16 + fr; rq = rq < 24 ? rq : 23;
            qa[t] = *reinterpret_cast<const bf16x8*>(qh + rq * 256 + fq * 8);
            ka[t] = *reinterpret_cast<const bf16x8*>(kh + rq * 256 + fq * 8);
        }

        {
            const int m = lane >> 2, q = lane & 3;
            const uint4 vv = *reinterpret_cast<const uint4*>(vh + m * 256 + q * 8);
            #pragma unroll
            for (int j = 0; j < 8; ++j) {
                const int f = q * 8 + j;
                Vt[swz(f, m >> 3) + (m & 7)] = reinterpret_cast<const u16*>(&vv)[j];
            }
            if (lane < 32) {
                const int m2 = 16 + (lane >> 2), q2 = lane & 3;
                const uint4 v2 = *reinterpret_cast<const uint4*>(vh + m2 * 256 + q2 * 8);
                #pragma unroll
                for (int j = 0; j < 8; ++j) {
                    const int f = q2 * 8 + j;
                    Vt[swz(f, m2 >> 3) + (m2 & 7)] = reinterpret_cast<const u16*>(&v2)[j];
                }
            }
        }

        f32x4 S[2][2];
        #pragma unroll
        for (int a = 0; a < 2; ++a)
            #pragma unroll
            for (int bb = 0; bb < 2; ++bb)
                S[a][bb] = __builtin_amdgcn_mfma_f32_16x16x32_bf16(
                    qa[a], ka[bb], (f32x4){0.f, 0.f, 0.f, 0.f}, 0, 0, 0);

        float inv[2][4];
        #pragma unroll
        for (int t = 0; t < 2; ++t) {
            float e0[4], e1[4];
            #pragma unroll
            for (int r = 0; r < 4; ++r) {
                const float a = S[t][0][r] * scale;
                const float bbv = colok ? S[t][1][r] * scale : -1e30f;
                float mx = fmaxf(a, bbv);
                #pragma unroll
                for (int off = 1; off < 16; off <<= 1)
                    mx = fmaxf(mx, __shfl_xor(mx, off));
                e0[r] = __expf(a - mx);
                e1[r] = colok ? __expf(bbv - mx) : 0.f;
                float sm = e0[r] + e1[r];
                #pragma unroll
                for (int off = 1; off < 16; off <<= 1)
                    sm += __shfl_xor(sm, off);
                inv[t][r] = 1.f / sm;
            }
            #pragma unroll
            for (int r = 0; r < 4; ++r) {
                const int row = t * 16 + fq * 4 + r;
                if (row < 24) {
                    Pw[swz(row, fr >> 3) + (fr & 7)] = f2b(e0[r]);
                    if (colok) {
                        const int c1 = 16 + fr;
                        Pw[swz(row, c1 >> 3) + (c1 & 7)] = f2b(e1[r]);
                    }
                }
            }
        }

        bf16x8 pa[2], vbf[2];
        #pragma unroll
        for (int t = 0; t < 2; ++t)
            pa[t] = *reinterpret_cast<const bf16x8*>(&Pw[swz(t * 16 + fr, fq)]);
        #pragma unroll
        for (int t = 0; t < 2; ++t)
            vbf[t] = *reinterpret_cast<const bf16x8*>(&Vt[swz(t * 16 + fr, fq)]);

        f32x4 O[2][2];
        #pragma unroll
        for (int a = 0; a < 2; ++a)
            #pragma unroll
            for (int bb = 0; bb < 2; ++bb)
                O[a][bb] = __builtin_amdgcn_mfma_f32_16x16x32_bf16(
                    pa[a], vbf[bb], (f32x4){0.f, 0.f, 0.f, 0.f}, 0, 0, 0);

        #pragma unroll
        for (int a = 0; a < 2; ++a)
            #pragma unroll
            for (int r = 0; r < 4; ++r) {
                const int row = a * 16 + fq * 4 + r;
                if (row < 24) {
                    outp[row * D_ + h * F_ + fr]      = O[a][0][r] * inv[a][r];
                    outp[row * D_ + h * F_ + 16 + fr] = O[a][1][r] * inv[a][r];
                }
            }
    }
}

extern "C" void kernel_launch(void* const* d_in, const int* in_sizes, int n_in,
                              void* d_out, int out_size, void* d_ws, size_t ws_size,
                              hipStream_t stream) {
    const float* x  = (const float*)d_in[0];
    const float* Wk = (const float*)d_in[1];
    const float* bk = (const float*)d_in[2];
    const float* Wv = (const float*)d_in[3];
    const float* bv = (const float*)d_in[4];
    const float* Wq = (const float*)d_in[5];
    const float* bq = (const float*)d_in[6];
    float* out = (float*)d_out;

    const size_t qkv_elems = (size_t)TB * HNF;
    const size_t need = qkv_elems * 2ull * 3ull;
    if (ws_size < need) fprintf(stderr, "ws too small: %zu < %zu\n", ws_size, need);
    u16* kbuf = (u16*)d_ws;
    u16* vbuf = kbuf + qkv_elems;
    u16* qbuf = vbuf + qkv_elems;

    // Bp (9.4 MB fp16) + biasp at head of d_out; attn overwrites all of d_out later
    u16*   Bp    = (u16*)d_out;
    float* biasp = (float*)((char*)d_out + (size_t)24 * 8 * 48 * 512 * 2);

    prep_weights<<<2304, 256, 0, stream>>>(Wk, Wv, Wq, Bp);
    prep_bias<<<(24 * 768 + 255) / 256, 256, 0, stream>>>(bk, bv, bq, biasp);
    proj_mfma<<<4608, 512, 0, stream>>>(x, Bp, biasp, kbuf, vbuf, qbuf);
    attn_mfma<<<TB / 4, 256, 0, stream>>>(kbuf, vbuf, qbuf, out);
}

// Round 10
// 284.808 us; speedup vs baseline: 4.6751x; 4.6751x over previous
//
#include <hip/hip_runtime.h>
#include <hip/hip_bf16.h>
#include <cstdio>

#define TB  8192
#define N_  24
#define D_  256
#define H_  8
#define F_  32
#define ND  6144      // N_*D_
#define HNF 6144      // H_*N_*F_

typedef unsigned short u16;
typedef __attribute__((ext_vector_type(8))) _Float16 f16x8;
typedef __attribute__((ext_vector_type(8))) short bf16x8;
typedef __attribute__((ext_vector_type(4))) float f32x4;

__device__ __forceinline__ u16 f2b(float f) {
    unsigned int u = __float_as_uint(f);
    return (u16)((u + 0x7FFFu + ((u >> 16) & 1u)) >> 16);
}
__device__ __forceinline__ float b2f(u16 s) {
    return __uint_as_float(((unsigned int)s) << 16);
}
__device__ __forceinline__ u16 f2h(float f) {
    _Float16 h = (_Float16)f;
    u16 u; __builtin_memcpy(&u, &h, 2); return u;
}

__device__ __forceinline__ void gl_lds16(const void* g, void* l) {
    __builtin_amdgcn_global_load_lds(
        (const __attribute__((address_space(1))) unsigned int*)g,
        (__attribute__((address_space(3))) unsigned int*)l, 16, 0, 0);
}

// ---------- prep: weights -> fp16, layout [n][kt][g(48)][fq(4)][fr(16)][8] ----------
__global__ __launch_bounds__(256) void prep_weights(
    const float* __restrict__ Wk, const float* __restrict__ Wv,
    const float* __restrict__ Wq, u16* __restrict__ Bp)
{
    const int idx = blockIdx.x * 256 + threadIdx.x;   // 0 .. 589823
    if (idx >= 24 * 8 * 48 * 64) return;
    const int fr = idx & 15;
    const int fq = (idx >> 4) & 3;
    const int g  = (idx >> 6) % 48;
    const int kt = (idx / (64 * 48)) % 8;
    const int n  = idx / (64 * 48 * 8);
    const int col = g * 16 + fr;
    const int d0  = kt * 32 + fq * 8;
    const int c   = col & 255;
    const float* src;
    if (col < 256)      src = Wk + (size_t)c * 256 + d0;
    else if (col < 512) src = Wv + (size_t)c * 256 + d0;
    else {
        const int h = c >> 5, f = c & 31;
        src = Wq + ((size_t)(h * 24 + n) * 32 + f) * 256 + d0;
    }
    __align__(16) u16 out[8];
    #pragma unroll
    for (int j = 0; j < 8; ++j) out[j] = f2h(src[j]);
    *reinterpret_cast<uint4*>(Bp + (size_t)idx * 8) =
        *reinterpret_cast<const uint4*>(out);
}

__global__ __launch_bounds__(256) void prep_bias(
    const float* __restrict__ bk, const float* __restrict__ bv,
    const float* __restrict__ bq, float* __restrict__ biasp)
{
    const int idx = blockIdx.x * 256 + threadIdx.x;
    if (idx >= 24 * 768) return;
    const int col = idx % 768, n = idx / 768;
    const int c = col & 255;
    float v;
    if (col < 256)      v = bk[c];
    else if (col < 512) v = bv[c];
    else { const int h = c >> 5, f = c & 31; v = bq[(h * 24 + n) * 32 + f]; }
    biasp[n * 768 + col] = v;
}

// ---------- proj v10: v7 pipeline + XCD-clustered groups + n-major output,
// 48KB LDS, launch_bounds(512,4) (DO NOT raise: (512,6) spilled acc -> 6x regress) ----------
__global__ __launch_bounds__(512, 4) void proj_mfma(
    const float* __restrict__ x,
    const u16* __restrict__ Bp,
    const float* __restrict__ biasp,
    u16* __restrict__ kb, u16* __restrict__ vb, u16* __restrict__ qb)
{
    // b = xcd + 8*(gi + 9*mblk); grp = xcd*9 + gi. Each XCD owns 9 groups
    // (= exactly 3 joints n) -> B slice 1.15MB L2-resident, x tiles shared.
    const int b    = blockIdx.x;                 // 0..4607
    const int xcd  = b & 7;
    const int t    = b >> 3;                     // 0..575
    const int gi   = t % 9;
    const int mblk = t / 9;                      // 0..63
    const int grp  = xcd * 9 + gi;               // 0..71
    const int n    = grp / 3;
    const int ct   = grp % 3;                    // 0=K,1=V,2=Q
    const int tb0  = mblk * 128;
    const int tid  = threadIdx.x;
    const int w    = tid >> 6;                   // 0..7
    const int lane = tid & 63;
    const int wm   = w >> 2;                     // row half
    const int wn   = w & 3;                      // col quarter
    const int fr   = lane & 15, fq = lane >> 4;

    // LDS 48KB: A dbuf 2x8KB [0,16K) | B dbuf 2x16KB [16K,48K).
    // Epilogue reuses [0,32K) for 64-row passes. 48KB -> up to 3 blocks/CU.
    __shared__ __align__(16) char smem[49152];
    char* const Ab = smem;
    char* const Bb = smem + 16384;

    // A staging: thread -> (row 0..127, chunk 0..3 of 8 fp16)
    const int arow = tid >> 2;
    const int ac   = tid & 3;
    const float* xsrc = x + (size_t)(tb0 + arow) * ND + n * 256 + ac * 8;
    const int awbyte = arow * 64 + ((ac ^ ((arow >> 1) & 3)) << 4);

    const size_t bbase = (size_t)(n * 8 * 48 + ct * 16 + w * 2) * 1024 + lane * 16;

    f32x4 acc[4][4];
    #pragma unroll
    for (int m = 0; m < 4; ++m)
        #pragma unroll
        for (int j = 0; j < 4; ++j) acc[m][j] = (f32x4){0.f, 0.f, 0.f, 0.f};

    float4 axr[2][2];  // static-indexed under full unroll

    // ---- prologue: A(0), B(0); write A(0); issue A(1) ----
    axr[0][0] = *reinterpret_cast<const float4*>(xsrc);
    axr[0][1] = *reinterpret_cast<const float4*>(xsrc + 4);
    gl_lds16((const char*)Bp + bbase,        Bb + (w * 2) * 1024);
    gl_lds16((const char*)Bp + bbase + 1024, Bb + (w * 2 + 1) * 1024);
    asm volatile("s_waitcnt vmcnt(2)" ::: "memory");   // A(0) regs ready
    {
        ushort4 hv, hv2;
        hv.x  = f2h(axr[0][0].x); hv.y  = f2h(axr[0][0].y);
        hv.z  = f2h(axr[0][0].z); hv.w  = f2h(axr[0][0].w);
        hv2.x = f2h(axr[0][1].x); hv2.y = f2h(axr[0][1].y);
        hv2.z = f2h(axr[0][1].z); hv2.w = f2h(axr[0][1].w);
        *reinterpret_cast<ushort4*>(Ab + awbyte)     = hv;
        *reinterpret_cast<ushort4*>(Ab + awbyte + 8) = hv2;
    }
    axr[1][0] = *reinterpret_cast<const float4*>(xsrc + 32);
    axr[1][1] = *reinterpret_cast<const float4*>(xsrc + 36);
    asm volatile("s_waitcnt lgkmcnt(0)" ::: "memory");
    asm volatile("s_waitcnt vmcnt(2)" ::: "memory");   // B(0) landed
    __builtin_amdgcn_s_barrier();
    asm volatile("" ::: "memory");

    #pragma unroll
    for (int kt = 0; kt < 8; ++kt) {
        const int c = kt & 1, o = c ^ 1;

        // issue B(kt+1) -> other buf (stays in flight across compute)
        if (kt < 7) {
            const size_t bs = bbase + (size_t)(kt + 1) * 48 * 1024;
            gl_lds16((const char*)Bp + bs,        Bb + o * 16384 + (w * 2) * 1024);
            gl_lds16((const char*)Bp + bs + 1024, Bb + o * 16384 + (w * 2 + 1) * 1024);
        }

        // ---- compute(kt): 8 ds_read_b128 + 16 MFMA ----
        f16x8 bfr[4], afr[4];
        #pragma unroll
        for (int j = 0; j < 4; ++j)
            bfr[j] = *reinterpret_cast<const f16x8*>(
                Bb + c * 16384 + (wn * 4 + j) * 1024 + lane * 16);
        #pragma unroll
        for (int m = 0; m < 4; ++m) {
            const int row = wm * 64 + m * 16 + fr;
            afr[m] = *reinterpret_cast<const f16x8*>(
                Ab + c * 8192 + row * 64 + ((fq ^ ((fr >> 1) & 3)) << 4));
        }
        __builtin_amdgcn_s_setprio(1);
        #pragma unroll
        for (int j = 0; j < 4; ++j)
            #pragma unroll
            for (int m = 0; m < 4; ++m)
                acc[m][j] = __builtin_amdgcn_mfma_f32_16x16x32_f16(
                    afr[m], bfr[j], acc[m][j], 0, 0, 0);
        __builtin_amdgcn_s_setprio(0);

        if (kt < 7) {
            // A(kt+1) regs ready (oldest 2 of [A(kt+1), B(kt+1)])
            asm volatile("s_waitcnt vmcnt(2)" ::: "memory");
            __builtin_amdgcn_sched_barrier(0);
            {
                const float4 lo = axr[(kt + 1) & 1][0];
                const float4 hi = axr[(kt + 1) & 1][1];
                ushort4 hv, hv2;
                hv.x  = f2h(lo.x); hv.y  = f2h(lo.y); hv.z  = f2h(lo.z); hv.w  = f2h(lo.w);
                hv2.x = f2h(hi.x); hv2.y = f2h(hi.y); hv2.z = f2h(hi.z); hv2.w = f2h(hi.w);
                *reinterpret_cast<ushort4*>(Ab + o * 8192 + awbyte)     = hv;
                *reinterpret_cast<ushort4*>(Ab + o * 8192 + awbyte + 8) = hv2;
            }
            if (kt < 6) {
                axr[kt & 1][0] = *reinterpret_cast<const float4*>(xsrc + (kt + 2) * 32);
                axr[kt & 1][1] = *reinterpret_cast<const float4*>(xsrc + (kt + 2) * 32 + 4);
            }
            asm volatile("s_waitcnt lgkmcnt(0)" ::: "memory");
            if (kt < 6) {
                asm volatile("s_waitcnt vmcnt(2)" ::: "memory");   // B(kt+1) landed
            } else {
                asm volatile("s_waitcnt vmcnt(0)" ::: "memory");   // tail: drain B(7)
            }
            __builtin_amdgcn_s_barrier();
            asm volatile("" ::: "memory");
        }
    }
    __syncthreads();

    // ---- epilogue: two 64-row passes through 32KB swizzled LDS,
    // n-major output: dst[tb*6144 + n*256 + c] -> 512B contiguous per row ----
    u16* dst = (ct == 0) ? kb : (ct == 1) ? vb : qb;
    #pragma unroll
    for (int p = 0; p < 2; ++p) {
        if (wm == p) {
            #pragma unroll
            for (int j = 0; j < 4; ++j) {
                const int colL = wn * 64 + j * 16 + fr;
                const float bs = biasp[n * 768 + ct * 256 + colL];
                #pragma unroll
                for (int m = 0; m < 4; ++m)
                    #pragma unroll
                    for (int r = 0; r < 4; ++r) {
                        const int rowL = m * 16 + fq * 4 + r;   // 0..63
                        const int byte = (rowL * 512 + colL * 2) ^ ((rowL & 7) << 4);
                        *reinterpret_cast<u16*>(smem + byte) = f2b(acc[m][j][r] + bs);
                    }
            }
        }
        __syncthreads();
        #pragma unroll
        for (int it = 0; it < 4; ++it) {
            const int id  = it * 512 + tid;      // 0..2047 16B chunks
            const int row = id >> 5;             // 0..63
            const int cch = id & 31;
            const uint4 v = *reinterpret_cast<const uint4*>(
                smem + ((row * 512 + cch * 16) ^ ((row & 7) << 4)));
            *reinterpret_cast<uint4*>(
                &dst[(size_t)(tb0 + p * 64 + row) * HNF + n * 256 + cch * 8]) = v;
        }
        __syncthreads();
    }
}

// ---------------- attention: MFMA, one wave per tb, barrier-free ----------------
// q/k/v layout per tb: [n(24)][h(8)][f(32)] (n-major, c = h*32+f contiguous).
__device__ __forceinline__ int swz(int row, int chunk) {
    return row * 32 + (((chunk ^ ((row >> 1) ^ (row >> 3))) & 3) << 3);
}

__global__ __launch_bounds__(256) void attn_mfma(
    const u16* __restrict__ kb,
    const u16* __restrict__ vb,
    const u16* __restrict__ qb,
    float* __restrict__ out)
{
    const int tid  = threadIdx.x;
    const int wid  = tid >> 6;
    const int lane = tid & 63;
    const int fr   = lane & 15;
    const int fq   = lane >> 4;
    const size_t tb = (size_t)blockIdx.x * 4 + wid;

    __shared__ __align__(16) u16 lds[4][2048];
    u16* Pw = lds[wid];
    u16* Vt = lds[wid] + 1024;

    #pragma unroll
    for (int i = 0; i < 4; ++i)
        reinterpret_cast<uint4*>(lds[wid])[lane + i * 64] = (uint4){0, 0, 0, 0};

    const u16* qt = qb + tb * HNF;
    const u16* kt = kb + tb * HNF;
    const u16* vt = vb + tb * HNF;
    float* outp = out + tb * ND;

    const float scale = 0.17677669529663687f;
    const bool colok = fr < 8;

    for (int h = 0; h < H_; ++h) {
        const u16* qh = qt + h * 32;     // + n*256 + f
        const u16* kh = kt + h * 32;
        const u16* vh = vt + h * 32;

        bf16x8 qa[2], ka[2];
        #pragma unroll
        for (int t = 0; t < 2; ++t) {
            int rq = t * 16 + fr; rq = rq < 24 ? rq : 23;
            qa[t] = *reinterpret_cast<const bf16x8*>(qh + rq * 256 + fq * 8);
            ka[t] = *reinterpret_cast<const bf16x8*>(kh + rq * 256 + fq * 8);
        }

        {
            const int m = lane >> 2, q = lane & 3;
            const uint4 vv = *reinterpret_cast<const uint4*>(vh + m * 256 + q * 8);
            #pragma unroll
            for (int j = 0; j < 8; ++j) {
                const int f = q * 8 + j;
                Vt[swz(f, m >> 3) + (m & 7)] = reinterpret_cast<const u16*>(&vv)[j];
            }
            if (lane < 32) {
                const int m2 = 16 + (lane >> 2), q2 = lane & 3;
                const uint4 v2 = *reinterpret_cast<const uint4*>(vh + m2 * 256 + q2 * 8);
                #pragma unroll
                for (int j = 0; j < 8; ++j) {
                    const int f = q2 * 8 + j;
                    Vt[swz(f, m2 >> 3) + (m2 & 7)] = reinterpret_cast<const u16*>(&v2)[j];
                }
            }
        }

        f32x4 S[2][2];
        #pragma unroll
        for (int a = 0; a < 2; ++a)
            #pragma unroll
            for (int bb = 0; bb < 2; ++bb)
                S[a][bb] = __builtin_amdgcn_mfma_f32_16x16x32_bf16(
                    qa[a], ka[bb], (f32x4){0.f, 0.f, 0.f, 0.f}, 0, 0, 0);

        float inv[2][4];
        #pragma unroll
        for (int t = 0; t < 2; ++t) {
            float e0[4], e1[4];
            #pragma unroll
            for (int r = 0; r < 4; ++r) {
                const float a = S[t][0][r] * scale;
                const float bbv = colok ? S[t][1][r] * scale : -1e30f;
                float mx = fmaxf(a, bbv);
                #pragma unroll
                for (int off = 1; off < 16; off <<= 1)
                    mx = fmaxf(mx, __shfl_xor(mx, off));
                e0[r] = __expf(a - mx);
                e1[r] = colok ? __expf(bbv - mx) : 0.f;
                float sm = e0[r] + e1[r];
                #pragma unroll
                for (int off = 1; off < 16; off <<= 1)
                    sm += __shfl_xor(sm, off);
                inv[t][r] = 1.f / sm;
            }
            #pragma unroll
            for (int r = 0; r < 4; ++r) {
                const int row = t * 16 + fq * 4 + r;
                if (row < 24) {
                    Pw[swz(row, fr >> 3) + (fr & 7)] = f2b(e0[r]);
                    if (colok) {
                        const int c1 = 16 + fr;
                        Pw[swz(row, c1 >> 3) + (c1 & 7)] = f2b(e1[r]);
                    }
                }
            }
        }

        bf16x8 pa[2], vbf[2];
        #pragma unroll
        for (int t = 0; t < 2; ++t)
            pa[t] = *reinterpret_cast<const bf16x8*>(&Pw[swz(t * 16 + fr, fq)]);
        #pragma unroll
        for (int t = 0; t < 2; ++t)
            vbf[t] = *reinterpret_cast<const bf16x8*>(&Vt[swz(t * 16 + fr, fq)]);

        f32x4 O[2][2];
        #pragma unroll
        for (int a = 0; a < 2; ++a)
            #pragma unroll
            for (int bb = 0; bb < 2; ++bb)
                O[a][bb] = __builtin_amdgcn_mfma_f32_16x16x32_bf16(
                    pa[a], vbf[bb], (f32x4){0.f, 0.f, 0.f, 0.f}, 0, 0, 0);

        #pragma unroll
        for (int a = 0; a < 2; ++a)
            #pragma unroll
            for (int r = 0; r < 4; ++r) {
                const int row = a * 16 + fq * 4 + r;
                if (row < 24) {
                    outp[row * D_ + h * F_ + fr]      = O[a][0][r] * inv[a][r];
                    outp[row * D_ + h * F_ + 16 + fr] = O[a][1][r] * inv[a][r];
                }
            }
    }
}

extern "C" void kernel_launch(void* const* d_in, const int* in_sizes, int n_in,
                              void* d_out, int out_size, void* d_ws, size_t ws_size,
                              hipStream_t stream) {
    const float* x  = (const float*)d_in[0];
    const float* Wk = (const float*)d_in[1];
    const float* bk = (const float*)d_in[2];
    const float* Wv = (const float*)d_in[3];
    const float* bv = (const float*)d_in[4];
    const float* Wq = (const float*)d_in[5];
    const float* bq = (const float*)d_in[6];
    float* out = (float*)d_out;

    const size_t qkv_elems = (size_t)TB * HNF;
    const size_t need = qkv_elems * 2ull * 3ull;
    if (ws_size < need) fprintf(stderr, "ws too small: %zu < %zu\n", ws_size, need);
    u16* kbuf = (u16*)d_ws;
    u16* vbuf = kbuf + qkv_elems;
    u16* qbuf = vbuf + qkv_elems;

    // Bp (9.4 MB fp16) + biasp at head of d_out; attn overwrites all of d_out later
    u16*   Bp    = (u16*)d_out;
    float* biasp = (float*)((char*)d_out + (size_t)24 * 8 * 48 * 512 * 2);

    prep_weights<<<2304, 256, 0, stream>>>(Wk, Wv, Wq, Bp);
    prep_bias<<<(24 * 768 + 255) / 256, 256, 0, stream>>>(bk, bv, bq, biasp);
    proj_mfma<<<4608, 512, 0, stream>>>(x, Bp, biasp, kbuf, vbuf, qbuf);
    attn_mfma<<<TB / 4, 256, 0, stream>>>(kbuf, vbuf, qbuf, out);
}